// Round 1
// baseline (467.017 us; speedup 1.0000x reference)
//
#include <hip/hip_runtime.h>
#include <math.h>

// DGNRNetwork: encoder MLP -> TransformerConv(32->4x32) -> mask -> TransformerConv(128->4x32) -> head
// N=50000, E=800000, B=1000, HID=32, HEADS=4, D1=128, FINAL=288

// ---------------- encoder: h0 = relu(relu(x@W1+b1)@W2+b2) ----------------
__global__ __launch_bounds__(256)
void enc_kernel(const float* __restrict__ x,
                const float* __restrict__ w1, const float* __restrict__ b1,
                const float* __restrict__ w2, const float* __restrict__ b2,
                float* __restrict__ h0, int n) {
    __shared__ float W1s[64 * 32];
    __shared__ float W2s[32 * 32];
    __shared__ float B1s[32], B2s[32];
    __shared__ float xs[8 * 64];
    __shared__ float hs[8 * 32];
    int t = threadIdx.x;
    for (int i = t; i < 64 * 32; i += 256) W1s[i] = w1[i];
    for (int i = t; i < 32 * 32; i += 256) W2s[i] = w2[i];
    if (t < 32) { B1s[t] = b1[t]; B2s[t] = b2[t]; }
    int bn = blockIdx.x * 8;
    if (t < 128) {  // 8 rows x 64 floats = 128 float4, contiguous
        int row = t >> 4;
        float4 val = make_float4(0.f, 0.f, 0.f, 0.f);
        if (bn + row < n) val = *(const float4*)(x + (size_t)bn * 64 + t * 4);
        ((float4*)xs)[t] = val;
    }
    __syncthreads();
    int nn = t >> 5, c = t & 31;
    float acc = B1s[c];
#pragma unroll
    for (int i = 0; i < 64; ++i) acc += xs[nn * 64 + i] * W1s[i * 32 + c];
    acc = fmaxf(acc, 0.f);
    hs[nn * 32 + c] = acc;
    __syncthreads();
    float acc2 = B2s[c];
#pragma unroll
    for (int i = 0; i < 32; ++i) acc2 += hs[nn * 32 + i] * W2s[i * 32 + c];
    acc2 = fmaxf(acc2, 0.f);
    int node = bn + nn;
    if (node < n) h0[(size_t)node * 32 + c] = acc2;
}

// ---------------- qkv GEMM: Y(z) = (X .* mask?) @ W(z) + b(z), OUT=128 ----------------
// 256 thr: ty=tid/16 (4 nodes each, rows ty*4..+3), tx=tid%16 (8 chans, tx+16j). BM=64, KT=32.
__global__ __launch_bounds__(256)
void qkv_kernel(const float* __restrict__ X, const float* __restrict__ mask,
                const float* __restrict__ Wq, const float* __restrict__ Bq,
                const float* __restrict__ Wk, const float* __restrict__ Bk,
                const float* __restrict__ Wv, const float* __restrict__ Bv,
                float* __restrict__ Q, float* __restrict__ K, float* __restrict__ V,
                int n, int IN) {
    const float* Wg; const float* Bg; float* Y;
    int z = blockIdx.y;
    if (z == 0)      { Wg = Wq; Bg = Bq; Y = Q; }
    else if (z == 1) { Wg = Wk; Bg = Bk; Y = K; }
    else             { Wg = Wv; Bg = Bv; Y = V; }
    __shared__ float Xs[64 * 33];     // +1 pad breaks bank conflicts on reads
    __shared__ float Ws[32 * 128];
    int t = threadIdx.x;
    int tx = t & 15, ty = t >> 4;
    int bm = blockIdx.x * 64;
    float acc[4][8];
#pragma unroll
    for (int i = 0; i < 4; ++i)
#pragma unroll
        for (int j = 0; j < 8; ++j) acc[i][j] = 0.f;

    for (int kt = 0; kt < IN; kt += 32) {
#pragma unroll
        for (int rep = 0; rep < 2; ++rep) {   // stage X tile 64x32 (scalar LDS writes into padded rows)
            int f4i = t + rep * 256;          // 0..511
            int r = f4i >> 3, qi = f4i & 7;
            int node = bm + r;
            float4 val = make_float4(0.f, 0.f, 0.f, 0.f);
            if (node < n) {
                val = *(const float4*)(X + (size_t)node * IN + kt + qi * 4);
                if (mask) { float mv = mask[node]; val.x *= mv; val.y *= mv; val.z *= mv; val.w *= mv; }
            }
            Xs[r * 33 + qi * 4 + 0] = val.x;
            Xs[r * 33 + qi * 4 + 1] = val.y;
            Xs[r * 33 + qi * 4 + 2] = val.z;
            Xs[r * 33 + qi * 4 + 3] = val.w;
        }
        {   // stage W tile 32x128 (contiguous 4096 floats)
            const float4* Wg4 = (const float4*)(Wg + (size_t)kt * 128);
            float4* Ws4 = (float4*)Ws;
#pragma unroll
            for (int rep = 0; rep < 4; ++rep) Ws4[t + rep * 256] = Wg4[t + rep * 256];
        }
        __syncthreads();
#pragma unroll
        for (int kk = 0; kk < 32; ++kk) {
            float xv[4], wv[8];
#pragma unroll
            for (int i = 0; i < 4; ++i) xv[i] = Xs[(ty * 4 + i) * 33 + kk];
#pragma unroll
            for (int j = 0; j < 8; ++j) wv[j] = Ws[kk * 128 + tx + 16 * j];
#pragma unroll
            for (int i = 0; i < 4; ++i)
#pragma unroll
                for (int j = 0; j < 8; ++j) acc[i][j] += xv[i] * wv[j];
        }
        __syncthreads();
    }
#pragma unroll
    for (int j = 0; j < 8; ++j) {
        float b = Bg[tx + 16 * j];
#pragma unroll
        for (int i = 0; i < 4; ++i) {
            int node = bm + ty * 4 + i;
            if (node < n) Y[(size_t)node * 128 + tx + 16 * j] = acc[i][j] + b;
        }
    }
}

// ---------------- CSR build ----------------
__global__ void hist_kernel(const int* __restrict__ dst, int* __restrict__ deg, int e) {
    int i = blockIdx.x * 256 + threadIdx.x;
    if (i < e) atomicAdd(&deg[dst[i]], 1);
}
__global__ void scan1_kernel(const int* __restrict__ deg, int* __restrict__ rp,
                             int* __restrict__ bsum, int n) {
    __shared__ int s[256];
    int t = threadIdx.x;
    int gid = blockIdx.x * 256 + t;
    int v = (gid < n) ? deg[gid] : 0;
    s[t] = v;
    __syncthreads();
#pragma unroll
    for (int off = 1; off < 256; off <<= 1) {
        int tv = (t >= off) ? s[t - off] : 0;
        __syncthreads();
        s[t] += tv;
        __syncthreads();
    }
    if (gid < n) rp[gid] = s[t] - v;            // exclusive within chunk
    if (t == 255) bsum[blockIdx.x] = s[255];    // chunk total
}
__global__ void scan2_kernel(int* bsum, int nb) {  // nb <= 256
    __shared__ int s[256];
    int t = threadIdx.x;
    int v = (t < nb) ? bsum[t] : 0;
    s[t] = v;
    __syncthreads();
#pragma unroll
    for (int off = 1; off < 256; off <<= 1) {
        int tv = (t >= off) ? s[t - off] : 0;
        __syncthreads();
        s[t] += tv;
        __syncthreads();
    }
    if (t < nb) bsum[t] = s[t] - v;             // exclusive
}
__global__ void scan3_kernel(int* rp, const int* __restrict__ bsum, int n) {
    int gid = blockIdx.x * 256 + threadIdx.x;
    if (gid < n) rp[gid] += bsum[blockIdx.x];
}
__global__ void scatter_kernel(const int* __restrict__ src, const int* __restrict__ dst,
                               const int* __restrict__ rp, int* __restrict__ cur,
                               int* __restrict__ col, int e) {
    int i = blockIdx.x * 256 + threadIdx.x;
    if (i < e) {
        int d = dst[i];
        int p = rp[d] + atomicAdd(&cur[d], 1);
        col[p] = src[i];
    }
}

// ---------------- attention: one wave per dst node, online softmax, relu fused ----------------
// lanes: es=lane>>5 (2 edge slots), within half: head=(lane>>3)&3, sub=lane&7 -> 4 dims; d0=(lane&31)*4
__global__ __launch_bounds__(256)
void attn_kernel(const float* __restrict__ q, const float* __restrict__ k,
                 const float* __restrict__ v,
                 const int* __restrict__ rp, const int* __restrict__ deg,
                 const int* __restrict__ col,
                 float* __restrict__ out, int n) {
    int w = threadIdx.x >> 6;
    int lane = threadIdx.x & 63;
    int node = blockIdx.x * 4 + w;
    if (node >= n) return;
    int es = lane >> 5;
    int d0 = (lane & 31) * 4;   // == head*32 + sub*4
    float4 qf = *(const float4*)(q + (size_t)node * 128 + d0);
    int start = rp[node], len = deg[node];
    float m = -INFINITY, s = 0.f;
    float4 acc = make_float4(0.f, 0.f, 0.f, 0.f);
    for (int i = es; i < len; i += 2) {
        int srcn = col[start + i];
        const float4 kf = *(const float4*)(k + (size_t)srcn * 128 + d0);
        float dot = qf.x * kf.x + qf.y * kf.y + qf.z * kf.z + qf.w * kf.w;
        dot += __shfl_xor(dot, 1);
        dot += __shfl_xor(dot, 2);
        dot += __shfl_xor(dot, 4);          // sum over the 8 lanes of this head
        float alpha = dot * 0.17677669529663689f;  // 1/sqrt(32)
        float nm = fmaxf(m, alpha);
        float fac = __expf(m - nm);         // m=-inf first iter -> 0
        float p = __expf(alpha - nm);
        const float4 vf = *(const float4*)(v + (size_t)srcn * 128 + d0);
        s = s * fac + p;
        acc.x = acc.x * fac + p * vf.x;
        acc.y = acc.y * fac + p * vf.y;
        acc.z = acc.z * fac + p * vf.z;
        acc.w = acc.w * fac + p * vf.w;
        m = nm;
    }
    // merge the two edge-slot halves (lane ^ 32)
    float mo = __shfl_xor(m, 32);
    float so = __shfl_xor(s, 32);
    float4 ao;
    ao.x = __shfl_xor(acc.x, 32); ao.y = __shfl_xor(acc.y, 32);
    ao.z = __shfl_xor(acc.z, 32); ao.w = __shfl_xor(acc.w, 32);
    float4 r = make_float4(0.f, 0.f, 0.f, 0.f);
    if (len > 0) {
        float nm = fmaxf(m, mo);            // finite: es=0 half always has >=1 edge
        float f1 = __expf(m - nm);
        float f2 = __expf(mo - nm);
        float inv = 1.f / (s * f1 + so * f2 + 1e-16f);
        r.x = fmaxf((acc.x * f1 + ao.x * f2) * inv, 0.f);
        r.y = fmaxf((acc.y * f1 + ao.y * f2) * inv, 0.f);
        r.z = fmaxf((acc.z * f1 + ao.z * f2) * inv, 0.f);
        r.w = fmaxf((acc.w * f1 + ao.w * f2) * inv, 0.f);
    }
    if (es == 0) *(float4*)(out + (size_t)node * 128 + d0) = r;
}

// ---------------- output head: concat(x1,x2,x3) @ out_w + out_b ----------------
__global__ void head_kernel(const float* __restrict__ h0, const float* __restrict__ h1,
                            const float* __restrict__ h2, const int* __restrict__ gi,
                            const float* __restrict__ ow, const float* __restrict__ ob,
                            float* __restrict__ out, int bsz) {
    int idx = blockIdx.x * 256 + threadIdx.x;
    if (idx >= bsz * 5) return;
    int b = idx / 5, c = idx % 5;
    int g = gi[b];
    float acc = ob[c];
    const float* r0 = h0 + (size_t)g * 32;
#pragma unroll
    for (int i = 0; i < 32; ++i) acc += r0[i] * ow[i * 5 + c];
    const float* r1 = h1 + (size_t)g * 128;
#pragma unroll
    for (int i = 0; i < 128; ++i) acc += r1[i] * ow[(32 + i) * 5 + c];
    const float* r2 = h2 + (size_t)g * 128;
#pragma unroll
    for (int i = 0; i < 128; ++i) acc += r2[i] * ow[(160 + i) * 5 + c];
    out[idx] = acc;
}

extern "C" void kernel_launch(void* const* d_in, const int* in_sizes, int n_in,
                              void* d_out, int out_size, void* d_ws, size_t ws_size,
                              hipStream_t stream) {
    const float* x    = (const float*)d_in[0];
    const int*   ei   = (const int*)d_in[1];
    const float* dm   = (const float*)d_in[2];
    const int*   gi   = (const int*)d_in[3];
    const float* ew1  = (const float*)d_in[4];
    const float* eb1  = (const float*)d_in[5];
    const float* ew2  = (const float*)d_in[6];
    const float* eb2  = (const float*)d_in[7];
    const float* c1wq = (const float*)d_in[8];
    const float* c1bq = (const float*)d_in[9];
    const float* c1wk = (const float*)d_in[10];
    const float* c1bk = (const float*)d_in[11];
    const float* c1wv = (const float*)d_in[12];
    const float* c1bv = (const float*)d_in[13];
    const float* c2wq = (const float*)d_in[14];
    const float* c2bq = (const float*)d_in[15];
    const float* c2wk = (const float*)d_in[16];
    const float* c2bk = (const float*)d_in[17];
    const float* c2wv = (const float*)d_in[18];
    const float* c2bv = (const float*)d_in[19];
    const float* ow   = (const float*)d_in[20];
    const float* ob   = (const float*)d_in[21];
    float* out = (float*)d_out;

    int N = in_sizes[0] / 64;
    int E = in_sizes[1] / 2;
    int B = in_sizes[3];
    const int* srcv = ei;
    const int* dstv = ei + E;

    // workspace carve-up (~140 MB)
    char* ws = (char*)d_ws;
    size_t off = 0;
    auto alloc = [&](size_t bytes) -> void* {
        void* p = ws + off;
        off += (bytes + 255) & ~(size_t)255;
        return p;
    };
    float* h0  = (float*)alloc((size_t)N * 32 * 4);
    float* h1  = (float*)alloc((size_t)N * 128 * 4);
    float* h2  = (float*)alloc((size_t)N * 128 * 4);
    float* Q   = (float*)alloc((size_t)N * 128 * 4);
    float* K   = (float*)alloc((size_t)N * 128 * 4);
    float* V   = (float*)alloc((size_t)N * 128 * 4);
    int* deg   = (int*)alloc((size_t)N * 4);
    int* rp    = (int*)alloc((size_t)N * 4);
    int* cur   = (int*)alloc((size_t)N * 4);
    int* colb  = (int*)alloc((size_t)E * 4);
    int* bsum  = (int*)alloc(4096);

    hipMemsetAsync(deg, 0, (size_t)N * 4, stream);
    hipMemsetAsync(cur, 0, (size_t)N * 4, stream);

    int eb = (E + 255) / 256;
    int nb = (N + 255) / 256;   // 196 <= 256 required by scan2
    hist_kernel<<<eb, 256, 0, stream>>>(dstv, deg, E);
    scan1_kernel<<<nb, 256, 0, stream>>>(deg, rp, bsum, N);
    scan2_kernel<<<1, 256, 0, stream>>>(bsum, nb);
    scan3_kernel<<<nb, 256, 0, stream>>>(rp, bsum, N);
    scatter_kernel<<<eb, 256, 0, stream>>>(srcv, dstv, rp, cur, colb, E);

    enc_kernel<<<(N + 7) / 8, 256, 0, stream>>>(x, ew1, eb1, ew2, eb2, h0, N);

    dim3 gq((N + 63) / 64, 3);
    // conv1: IN=32
    qkv_kernel<<<gq, 256, 0, stream>>>(h0, nullptr, c1wq, c1bq, c1wk, c1bk, c1wv, c1bv,
                                       Q, K, V, N, 32);
    attn_kernel<<<(N + 3) / 4, 256, 0, stream>>>(Q, K, V, rp, deg, colb, h1, N);
    // conv2: IN=128, input = h1 * dm_mask (mask fused into staging; x2 gathers unmasked h1)
    qkv_kernel<<<gq, 256, 0, stream>>>(h1, dm, c2wq, c2bq, c2wk, c2bk, c2wv, c2bv,
                                       Q, K, V, N, 128);
    attn_kernel<<<(N + 3) / 4, 256, 0, stream>>>(Q, K, V, rp, deg, colb, h2, N);

    head_kernel<<<(B * 5 + 255) / 256, 256, 0, stream>>>(h0, h1, h2, gi, ow, ob, out, B);
}

// Round 2
// 403.222 us; speedup vs baseline: 1.1582x; 1.1582x over previous
//
#include <hip/hip_runtime.h>
#include <math.h>

// DGNRNetwork: encoder MLP -> TransformerConv(32->4x32) -> mask -> TransformerConv(128->4x32) -> head
// N=50000, E=800000, B=1000, HID=32, HEADS=4, D1=128, FINAL=288
// K/V stored fp16 to halve the per-edge gather traffic (threshold 1.9e-2 >> fp16 err ~1e-3).

typedef _Float16 half8 __attribute__((ext_vector_type(8)));

// ---------------- encoder: h0 = relu(relu(x@W1+b1)@W2+b2) ----------------
__global__ __launch_bounds__(256)
void enc_kernel(const float* __restrict__ x,
                const float* __restrict__ w1, const float* __restrict__ b1,
                const float* __restrict__ w2, const float* __restrict__ b2,
                float* __restrict__ h0, int n) {
    __shared__ float W1s[64 * 32];
    __shared__ float W2s[32 * 32];
    __shared__ float B1s[32], B2s[32];
    __shared__ float xs[8 * 64];
    __shared__ float hs[8 * 32];
    int t = threadIdx.x;
    for (int i = t; i < 64 * 32; i += 256) W1s[i] = w1[i];
    for (int i = t; i < 32 * 32; i += 256) W2s[i] = w2[i];
    if (t < 32) { B1s[t] = b1[t]; B2s[t] = b2[t]; }
    int bn = blockIdx.x * 8;
    if (t < 128) {  // 8 rows x 64 floats = 128 float4, contiguous
        int row = t >> 4;
        float4 val = make_float4(0.f, 0.f, 0.f, 0.f);
        if (bn + row < n) val = *(const float4*)(x + (size_t)bn * 64 + t * 4);
        ((float4*)xs)[t] = val;
    }
    __syncthreads();
    int nn = t >> 5, c = t & 31;
    float acc = B1s[c];
#pragma unroll
    for (int i = 0; i < 64; ++i) acc += xs[nn * 64 + i] * W1s[i * 32 + c];
    acc = fmaxf(acc, 0.f);
    hs[nn * 32 + c] = acc;
    __syncthreads();
    float acc2 = B2s[c];
#pragma unroll
    for (int i = 0; i < 32; ++i) acc2 += hs[nn * 32 + i] * W2s[i * 32 + c];
    acc2 = fmaxf(acc2, 0.f);
    int node = bn + nn;
    if (node < n) h0[(size_t)node * 32 + c] = acc2;
}

// ---------------- fused qkv GEMM: {Q,K,V} = (X .* mask?) @ W{q,k,v} + b, OUT=128 ----------------
// 256 thr: ty=t/16 -> 4 node rows each; tx=t%16 -> 8 contiguous chans (tx*8+j). BM=64, KT=32.
// Q written f32; K,V written fp16.
__global__ __launch_bounds__(256)
void qkv_kernel(const float* __restrict__ X, const float* __restrict__ mask,
                const float* __restrict__ Wq, const float* __restrict__ Bq,
                const float* __restrict__ Wk, const float* __restrict__ Bk,
                const float* __restrict__ Wv, const float* __restrict__ Bv,
                float* __restrict__ Q, _Float16* __restrict__ K, _Float16* __restrict__ V,
                int n, int IN) {
    __shared__ float Xs[64 * 33];      // +1 pad breaks bank conflicts on reads
    __shared__ float Ws[3][32 * 128];
    const float* Wg[3] = {Wq, Wk, Wv};
    const float* Bg[3] = {Bq, Bk, Bv};
    int t = threadIdx.x;
    int tx = t & 15, ty = t >> 4;
    int bm = blockIdx.x * 64;
    float acc[3][4][8];
#pragma unroll
    for (int z = 0; z < 3; ++z)
#pragma unroll
        for (int i = 0; i < 4; ++i)
#pragma unroll
            for (int j = 0; j < 8; ++j) acc[z][i][j] = 0.f;

    for (int kt = 0; kt < IN; kt += 32) {
#pragma unroll
        for (int rep = 0; rep < 2; ++rep) {   // stage X tile 64x32
            int f4i = t + rep * 256;          // 0..511
            int r = f4i >> 3, qi = f4i & 7;
            int node = bm + r;
            float4 val = make_float4(0.f, 0.f, 0.f, 0.f);
            if (node < n) {
                val = *(const float4*)(X + (size_t)node * IN + kt + qi * 4);
                if (mask) { float mv = mask[node]; val.x *= mv; val.y *= mv; val.z *= mv; val.w *= mv; }
            }
            Xs[r * 33 + qi * 4 + 0] = val.x;
            Xs[r * 33 + qi * 4 + 1] = val.y;
            Xs[r * 33 + qi * 4 + 2] = val.z;
            Xs[r * 33 + qi * 4 + 3] = val.w;
        }
#pragma unroll
        for (int z = 0; z < 3; ++z) {   // stage W tiles 32x128 (contiguous)
            const float4* Wg4 = (const float4*)(Wg[z] + (size_t)kt * 128);
            float4* Ws4 = (float4*)Ws[z];
#pragma unroll
            for (int rep = 0; rep < 4; ++rep) Ws4[t + rep * 256] = Wg4[t + rep * 256];
        }
        __syncthreads();
#pragma unroll
        for (int kk = 0; kk < 32; ++kk) {
            float xv[4];
#pragma unroll
            for (int i = 0; i < 4; ++i) xv[i] = Xs[(ty * 4 + i) * 33 + kk];
#pragma unroll
            for (int z = 0; z < 3; ++z) {
                float4 w0 = *(const float4*)&Ws[z][kk * 128 + tx * 8];
                float4 w1 = *(const float4*)&Ws[z][kk * 128 + tx * 8 + 4];
#pragma unroll
                for (int i = 0; i < 4; ++i) {
                    acc[z][i][0] += xv[i] * w0.x; acc[z][i][1] += xv[i] * w0.y;
                    acc[z][i][2] += xv[i] * w0.z; acc[z][i][3] += xv[i] * w0.w;
                    acc[z][i][4] += xv[i] * w1.x; acc[z][i][5] += xv[i] * w1.y;
                    acc[z][i][6] += xv[i] * w1.z; acc[z][i][7] += xv[i] * w1.w;
                }
            }
        }
        __syncthreads();
    }
    float bq[8], bk[8], bv[8];
#pragma unroll
    for (int j = 0; j < 8; ++j) { bq[j] = Bg[0][tx * 8 + j]; bk[j] = Bg[1][tx * 8 + j]; bv[j] = Bg[2][tx * 8 + j]; }
#pragma unroll
    for (int i = 0; i < 4; ++i) {
        int node = bm + ty * 4 + i;
        if (node >= n) continue;
        float4 q0, q1;
        q0.x = acc[0][i][0] + bq[0]; q0.y = acc[0][i][1] + bq[1];
        q0.z = acc[0][i][2] + bq[2]; q0.w = acc[0][i][3] + bq[3];
        q1.x = acc[0][i][4] + bq[4]; q1.y = acc[0][i][5] + bq[5];
        q1.z = acc[0][i][6] + bq[6]; q1.w = acc[0][i][7] + bq[7];
        *(float4*)(Q + (size_t)node * 128 + tx * 8) = q0;
        *(float4*)(Q + (size_t)node * 128 + tx * 8 + 4) = q1;
        half8 kh, vh;
#pragma unroll
        for (int j = 0; j < 8; ++j) {
            kh[j] = (_Float16)(acc[1][i][j] + bk[j]);
            vh[j] = (_Float16)(acc[2][i][j] + bv[j]);
        }
        *(half8*)(K + (size_t)node * 128 + tx * 8) = kh;
        *(half8*)(V + (size_t)node * 128 + tx * 8) = vh;
    }
}

// ---------------- CSR build ----------------
__global__ void hist_kernel(const int* __restrict__ dst, int* __restrict__ deg, int e) {
    int i = blockIdx.x * 256 + threadIdx.x;
    if (i < e) atomicAdd(&deg[dst[i]], 1);
}
__global__ void scan1_kernel(const int* __restrict__ deg, int* __restrict__ rp,
                             int* __restrict__ bsum, int n) {
    __shared__ int s[256];
    int t = threadIdx.x;
    int gid = blockIdx.x * 256 + t;
    int v = (gid < n) ? deg[gid] : 0;
    s[t] = v;
    __syncthreads();
#pragma unroll
    for (int off = 1; off < 256; off <<= 1) {
        int tv = (t >= off) ? s[t - off] : 0;
        __syncthreads();
        s[t] += tv;
        __syncthreads();
    }
    if (gid < n) rp[gid] = s[t] - v;            // exclusive within chunk
    if (t == 255) bsum[blockIdx.x] = s[255];    // chunk total
}
__global__ void scan2_kernel(int* bsum, int nb) {  // nb <= 256
    __shared__ int s[256];
    int t = threadIdx.x;
    int v = (t < nb) ? bsum[t] : 0;
    s[t] = v;
    __syncthreads();
#pragma unroll
    for (int off = 1; off < 256; off <<= 1) {
        int tv = (t >= off) ? s[t - off] : 0;
        __syncthreads();
        s[t] += tv;
        __syncthreads();
    }
    if (t < nb) bsum[t] = s[t] - v;             // exclusive
}
__global__ void scan3_kernel(int* rp, const int* __restrict__ bsum, int n) {
    int gid = blockIdx.x * 256 + threadIdx.x;
    if (gid < n) rp[gid] += bsum[blockIdx.x];
}
__global__ void scatter_kernel(const int* __restrict__ src, const int* __restrict__ dst,
                               const int* __restrict__ rp, int* __restrict__ cur,
                               int* __restrict__ col, int e) {
    int i = blockIdx.x * 256 + threadIdx.x;
    if (i < e) {
        int d = dst[i];
        int p = rp[d] + atomicAdd(&cur[d], 1);
        col[p] = src[i];
    }
}

// ---------------- attention: one wave per dst node, 4 edge slots, online softmax, relu fused ----
// lane: es=lane>>4 (4 edge slots); l=lane&15 -> 8 dims at d0=l*8; head = l>>2 (4 lanes x 8 dims = 32)
__global__ __launch_bounds__(256)
void attn_kernel(const float* __restrict__ q, const _Float16* __restrict__ k,
                 const _Float16* __restrict__ v,
                 const int* __restrict__ rp, const int* __restrict__ deg,
                 const int* __restrict__ col,
                 float* __restrict__ out, int n) {
    int w = threadIdx.x >> 6;
    int lane = threadIdx.x & 63;
    int node = blockIdx.x * 4 + w;
    if (node >= n) return;
    int es = lane >> 4;
    int l = lane & 15;
    int d0 = l * 8;
    float qf[8];
    {
        float4 q0 = *(const float4*)(q + (size_t)node * 128 + d0);
        float4 q1 = *(const float4*)(q + (size_t)node * 128 + d0 + 4);
        qf[0] = q0.x; qf[1] = q0.y; qf[2] = q0.z; qf[3] = q0.w;
        qf[4] = q1.x; qf[5] = q1.y; qf[6] = q1.z; qf[7] = q1.w;
    }
    int start = rp[node], len = deg[node];
    float m = -1e30f, s = 0.f;
    float acc[8];
#pragma unroll
    for (int j = 0; j < 8; ++j) acc[j] = 0.f;

    for (int i = es; i < len; i += 4) {
        int srcn = col[start + i];
        half8 kf = *(const half8*)(k + (size_t)srcn * 128 + d0);
        float dot = 0.f;
#pragma unroll
        for (int j = 0; j < 8; ++j) dot += qf[j] * (float)kf[j];
        dot += __shfl_xor(dot, 1);
        dot += __shfl_xor(dot, 2);            // sum over the 4 lanes of this head
        float alpha = dot * 0.17677669529663689f;  // 1/sqrt(32)
        float nm = fmaxf(m, alpha);
        float fac = __expf(m - nm);           // m=-1e30 first iter -> 0
        float p = __expf(alpha - nm);
        half8 vf = *(const half8*)(v + (size_t)srcn * 128 + d0);
        s = s * fac + p;
#pragma unroll
        for (int j = 0; j < 8; ++j) acc[j] = acc[j] * fac + p * (float)vf[j];
        m = nm;
    }
    // merge the four edge slots (lane ^ 16, lane ^ 32)
#pragma unroll
    for (int half = 16; half <= 32; half <<= 1) {
        float mo = __shfl_xor(m, half);
        float so = __shfl_xor(s, half);
        float ao[8];
#pragma unroll
        for (int j = 0; j < 8; ++j) ao[j] = __shfl_xor(acc[j], half);
        float nm = fmaxf(m, mo);
        float f1 = __expf(m - nm);
        float f2 = __expf(mo - nm);
        s = s * f1 + so * f2;
#pragma unroll
        for (int j = 0; j < 8; ++j) acc[j] = acc[j] * f1 + ao[j] * f2;
        m = nm;
    }
    if (es == 0) {
        float inv = 1.f / (s + 1e-16f);
        float4 r0, r1;
        r0.x = fmaxf(acc[0] * inv, 0.f); r0.y = fmaxf(acc[1] * inv, 0.f);
        r0.z = fmaxf(acc[2] * inv, 0.f); r0.w = fmaxf(acc[3] * inv, 0.f);
        r1.x = fmaxf(acc[4] * inv, 0.f); r1.y = fmaxf(acc[5] * inv, 0.f);
        r1.z = fmaxf(acc[6] * inv, 0.f); r1.w = fmaxf(acc[7] * inv, 0.f);
        *(float4*)(out + (size_t)node * 128 + d0) = r0;
        *(float4*)(out + (size_t)node * 128 + d0 + 4) = r1;
    }
}

// ---------------- output head: concat(x1,x2,x3) @ out_w + out_b ----------------
__global__ void head_kernel(const float* __restrict__ h0, const float* __restrict__ h1,
                            const float* __restrict__ h2, const int* __restrict__ gi,
                            const float* __restrict__ ow, const float* __restrict__ ob,
                            float* __restrict__ out, int bsz) {
    int idx = blockIdx.x * 256 + threadIdx.x;
    if (idx >= bsz * 5) return;
    int b = idx / 5, c = idx % 5;
    int g = gi[b];
    float acc = ob[c];
    const float* r0 = h0 + (size_t)g * 32;
#pragma unroll
    for (int i = 0; i < 32; ++i) acc += r0[i] * ow[i * 5 + c];
    const float* r1 = h1 + (size_t)g * 128;
#pragma unroll
    for (int i = 0; i < 128; ++i) acc += r1[i] * ow[(32 + i) * 5 + c];
    const float* r2 = h2 + (size_t)g * 128;
#pragma unroll
    for (int i = 0; i < 128; ++i) acc += r2[i] * ow[(160 + i) * 5 + c];
    out[idx] = acc;
}

extern "C" void kernel_launch(void* const* d_in, const int* in_sizes, int n_in,
                              void* d_out, int out_size, void* d_ws, size_t ws_size,
                              hipStream_t stream) {
    const float* x    = (const float*)d_in[0];
    const int*   ei   = (const int*)d_in[1];
    const float* dm   = (const float*)d_in[2];
    const int*   gi   = (const int*)d_in[3];
    const float* ew1  = (const float*)d_in[4];
    const float* eb1  = (const float*)d_in[5];
    const float* ew2  = (const float*)d_in[6];
    const float* eb2  = (const float*)d_in[7];
    const float* c1wq = (const float*)d_in[8];
    const float* c1bq = (const float*)d_in[9];
    const float* c1wk = (const float*)d_in[10];
    const float* c1bk = (const float*)d_in[11];
    const float* c1wv = (const float*)d_in[12];
    const float* c1bv = (const float*)d_in[13];
    const float* c2wq = (const float*)d_in[14];
    const float* c2bq = (const float*)d_in[15];
    const float* c2wk = (const float*)d_in[16];
    const float* c2bk = (const float*)d_in[17];
    const float* c2wv = (const float*)d_in[18];
    const float* c2bv = (const float*)d_in[19];
    const float* ow   = (const float*)d_in[20];
    const float* ob   = (const float*)d_in[21];
    float* out = (float*)d_out;

    int N = in_sizes[0] / 64;
    int E = in_sizes[1] / 2;
    int B = in_sizes[3];
    const int* srcv = ei;
    const int* dstv = ei + E;

    // workspace carve-up
    char* ws = (char*)d_ws;
    size_t off = 0;
    auto alloc = [&](size_t bytes) -> void* {
        void* p = ws + off;
        off += (bytes + 255) & ~(size_t)255;
        return p;
    };
    float*     h0  = (float*)alloc((size_t)N * 32 * 4);
    float*     h1  = (float*)alloc((size_t)N * 128 * 4);
    float*     h2  = (float*)alloc((size_t)N * 128 * 4);
    float*     Q   = (float*)alloc((size_t)N * 128 * 4);
    _Float16*  K   = (_Float16*)alloc((size_t)N * 128 * 2);
    _Float16*  V   = (_Float16*)alloc((size_t)N * 128 * 2);
    int* deg   = (int*)alloc((size_t)N * 4);
    int* rp    = (int*)alloc((size_t)N * 4);
    int* cur   = (int*)alloc((size_t)N * 4);
    int* colb  = (int*)alloc((size_t)E * 4);
    int* bsum  = (int*)alloc(4096);

    hipMemsetAsync(deg, 0, (size_t)N * 4, stream);
    hipMemsetAsync(cur, 0, (size_t)N * 4, stream);

    int eb = (E + 255) / 256;
    int nb = (N + 255) / 256;   // 196 <= 256 required by scan2
    hist_kernel<<<eb, 256, 0, stream>>>(dstv, deg, E);
    scan1_kernel<<<nb, 256, 0, stream>>>(deg, rp, bsum, N);
    scan2_kernel<<<1, 256, 0, stream>>>(bsum, nb);
    scan3_kernel<<<nb, 256, 0, stream>>>(rp, bsum, N);
    scatter_kernel<<<eb, 256, 0, stream>>>(srcv, dstv, rp, cur, colb, E);

    enc_kernel<<<(N + 7) / 8, 256, 0, stream>>>(x, ew1, eb1, ew2, eb2, h0, N);

    int gq = (N + 63) / 64;
    // conv1: IN=32
    qkv_kernel<<<gq, 256, 0, stream>>>(h0, nullptr, c1wq, c1bq, c1wk, c1bk, c1wv, c1bv,
                                       Q, K, V, N, 32);
    attn_kernel<<<(N + 3) / 4, 256, 0, stream>>>(Q, K, V, rp, deg, colb, h1, N);
    // conv2: IN=128, input = h1 * dm_mask (mask fused into staging; x2 gathers unmasked h1)
    qkv_kernel<<<gq, 256, 0, stream>>>(h1, dm, c2wq, c2bq, c2wk, c2bk, c2wv, c2bv,
                                       Q, K, V, N, 128);
    attn_kernel<<<(N + 3) / 4, 256, 0, stream>>>(Q, K, V, rp, deg, colb, h2, N);

    head_kernel<<<(B * 5 + 255) / 256, 256, 0, stream>>>(h0, h1, h2, gi, ow, ob, out, B);
}

// Round 3
// 285.836 us; speedup vs baseline: 1.6339x; 1.4107x over previous
//
#include <hip/hip_runtime.h>
#include <math.h>

// DGNRNetwork: encoder MLP -> TransformerConv(32->4x32) -> mask -> TransformerConv(128->4x32) -> head
// N=50000, E=800000, B=1000, HID=32, HEADS=4, D1=128, FINAL=288
// fp16 everywhere downstream of the encoder (threshold 1.9e-2 >> fp16 err); qkv via MFMA 16x16x32_f16.

typedef _Float16 half8 __attribute__((ext_vector_type(8)));
typedef float f32x4 __attribute__((ext_vector_type(4)));

__device__ inline half8 h8zero() {
    half8 r;
#pragma unroll
    for (int j = 0; j < 8; ++j) r[j] = (_Float16)0.f;
    return r;
}

// ---------------- encoder: h0 = relu(relu(x@W1+b1)@W2+b2), fp16 out ----------------
__global__ __launch_bounds__(256)
void enc_kernel(const float* __restrict__ x,
                const float* __restrict__ w1, const float* __restrict__ b1,
                const float* __restrict__ w2, const float* __restrict__ b2,
                _Float16* __restrict__ h0, int n) {
    __shared__ float W1s[64 * 32];
    __shared__ float W2s[32 * 32];
    __shared__ float B1s[32], B2s[32];
    __shared__ float xs[8 * 64];
    __shared__ float hs[8 * 32];
    int t = threadIdx.x;
    for (int i = t; i < 64 * 32; i += 256) W1s[i] = w1[i];
    for (int i = t; i < 32 * 32; i += 256) W2s[i] = w2[i];
    if (t < 32) { B1s[t] = b1[t]; B2s[t] = b2[t]; }
    int bn = blockIdx.x * 8;
    if (t < 128) {  // 8 rows x 64 floats = 128 float4, contiguous
        int row = t >> 4;
        float4 val = make_float4(0.f, 0.f, 0.f, 0.f);
        if (bn + row < n) val = *(const float4*)(x + (size_t)bn * 64 + t * 4);
        ((float4*)xs)[t] = val;
    }
    __syncthreads();
    int nn = t >> 5, c = t & 31;
    float acc = B1s[c];
#pragma unroll
    for (int i = 0; i < 64; ++i) acc += xs[nn * 64 + i] * W1s[i * 32 + c];
    acc = fmaxf(acc, 0.f);
    hs[nn * 32 + c] = acc;
    __syncthreads();
    float acc2 = B2s[c];
#pragma unroll
    for (int i = 0; i < 32; ++i) acc2 += hs[nn * 32 + i] * W2s[i * 32 + c];
    acc2 = fmaxf(acc2, 0.f);
    int node = bn + nn;
    if (node < n) h0[(size_t)node * 32 + c] = (_Float16)acc2;
}

// ---------------- weight transpose+convert: WT[z*128+c][k] = Wz[k][c] (fp16) ----------------
__global__ void wt_kernel(const float* __restrict__ wq, const float* __restrict__ wk,
                          const float* __restrict__ wv, _Float16* __restrict__ WT, int IN) {
    int tid = blockIdx.x * 256 + threadIdx.x;
    int total = 3 * 128 * IN;
    if (tid >= total) return;
    int z = tid / (128 * IN);
    int rem = tid % (128 * IN);
    int c = rem / IN;
    int k = rem % IN;
    const float* w = (z == 0) ? wq : ((z == 1) ? wk : wv);
    WT[tid] = (_Float16)w[k * 128 + c];
}

// ---------------- qkv GEMM via MFMA: {Q,K,V}[n x 128] = (X .* mask?) @ W + b -------------
// grid (ceil(n/64), 6): by>>1 = z (Q/K/V), (by&1)*64 = col base. 256 thr = 4 waves (2x2 of 32x32).
// A-frag: lane row=l&15, k=(l>>4)*8+j ; B-frag: lane col=l&15, same k ; C/D: col=l&15, row=(l>>4)*4+reg.
__global__ __launch_bounds__(256)
void qkv_kernel(const _Float16* __restrict__ X, const float* __restrict__ mask,
                const _Float16* __restrict__ WT,
                const float* __restrict__ Bq, const float* __restrict__ Bk,
                const float* __restrict__ Bv,
                _Float16* __restrict__ Q, _Float16* __restrict__ K, _Float16* __restrict__ V,
                int n, int IN) {
    __shared__ _Float16 Xs[64 * 40];   // 64 rows x 32 halfs, padded to 40 (conflict-free quads)
    __shared__ _Float16 Ws[64 * 40];
    int t = threadIdx.x;
    int z = blockIdx.y >> 1;
    int c0 = (blockIdx.y & 1) * 64;
    int bm = blockIdx.x * 64;
    _Float16* Y = (z == 0) ? Q : ((z == 1) ? K : V);
    const float* Bz = (z == 0) ? Bq : ((z == 1) ? Bk : Bv);
    int lane = t & 63, w = t >> 6;
    int wr = w >> 1, wc = w & 1;
    int fr = lane & 15, k0 = (lane >> 4) * 8;
    f32x4 acc[2][2];
#pragma unroll
    for (int i = 0; i < 2; ++i)
#pragma unroll
        for (int j = 0; j < 2; ++j)
#pragma unroll
            for (int r = 0; r < 4; ++r) acc[i][j][r] = 0.f;

    // staging role: thread t -> row t>>2, halfs (t&3)*8 .. +7
    int srow = t >> 2, sseg = (t & 3) * 8;
    int snode = bm + srow;
    const _Float16* xbase = X + (size_t)snode * IN + sseg;
    const _Float16* wbase = WT + (size_t)(z * 128 + c0 + srow) * IN + sseg;
    bool xvalid = (snode < n);
    if (xvalid && mask) xvalid = (mask[snode] != 0.f);   // mask is exactly 0/1

    for (int kt = 0; kt < IN; kt += 32) {
        half8 xv = h8zero();
        if (xvalid) xv = *(const half8*)(xbase + kt);
        half8 wv = *(const half8*)(wbase + kt);
        __syncthreads();   // protect LDS reuse from previous iteration
        *(half8*)&Xs[srow * 40 + sseg] = xv;
        *(half8*)&Ws[srow * 40 + sseg] = wv;
        __syncthreads();
        half8 a0 = *(const half8*)&Xs[(wr * 32 + fr) * 40 + k0];
        half8 a1 = *(const half8*)&Xs[(wr * 32 + 16 + fr) * 40 + k0];
        half8 b0 = *(const half8*)&Ws[(wc * 32 + fr) * 40 + k0];
        half8 b1 = *(const half8*)&Ws[(wc * 32 + 16 + fr) * 40 + k0];
        acc[0][0] = __builtin_amdgcn_mfma_f32_16x16x32_f16(a0, b0, acc[0][0], 0, 0, 0);
        acc[0][1] = __builtin_amdgcn_mfma_f32_16x16x32_f16(a0, b1, acc[0][1], 0, 0, 0);
        acc[1][0] = __builtin_amdgcn_mfma_f32_16x16x32_f16(a1, b0, acc[1][0], 0, 0, 0);
        acc[1][1] = __builtin_amdgcn_mfma_f32_16x16x32_f16(a1, b1, acc[1][1], 0, 0, 0);
    }
#pragma unroll
    for (int tr = 0; tr < 2; ++tr)
#pragma unroll
        for (int tc = 0; tc < 2; ++tc) {
            int col = c0 + wc * 32 + tc * 16 + fr;
            float bias = Bz[col];
#pragma unroll
            for (int reg = 0; reg < 4; ++reg) {
                int node = bm + wr * 32 + tr * 16 + (lane >> 4) * 4 + reg;
                if (node < n) Y[(size_t)node * 128 + col] = (_Float16)(acc[tr][tc][reg] + bias);
            }
        }
}

// ---------------- CSR build ----------------
__global__ void hist_kernel(const int* __restrict__ dst, int* __restrict__ deg, int e) {
    int i = blockIdx.x * 256 + threadIdx.x;
    if (i < e) atomicAdd(&deg[dst[i]], 1);
}
__global__ void scan1_kernel(const int* __restrict__ deg, int* __restrict__ rp,
                             int* __restrict__ bsum, int n) {
    __shared__ int s[256];
    int t = threadIdx.x;
    int gid = blockIdx.x * 256 + t;
    int v = (gid < n) ? deg[gid] : 0;
    s[t] = v;
    __syncthreads();
#pragma unroll
    for (int off = 1; off < 256; off <<= 1) {
        int tv = (t >= off) ? s[t - off] : 0;
        __syncthreads();
        s[t] += tv;
        __syncthreads();
    }
    if (gid < n) rp[gid] = s[t] - v;            // exclusive within chunk
    if (t == 255) bsum[blockIdx.x] = s[255];    // chunk total
}
__global__ void scan2_kernel(int* bsum, int nb) {  // nb <= 256
    __shared__ int s[256];
    int t = threadIdx.x;
    int v = (t < nb) ? bsum[t] : 0;
    s[t] = v;
    __syncthreads();
#pragma unroll
    for (int off = 1; off < 256; off <<= 1) {
        int tv = (t >= off) ? s[t - off] : 0;
        __syncthreads();
        s[t] += tv;
        __syncthreads();
    }
    if (t < nb) bsum[t] = s[t] - v;             // exclusive
}
__global__ void scan3_kernel(int* rp, const int* __restrict__ bsum, int n) {
    int gid = blockIdx.x * 256 + threadIdx.x;
    if (gid < n) rp[gid] += bsum[blockIdx.x];
}
__global__ void scatter_kernel(const int* __restrict__ src, const int* __restrict__ dst,
                               const int* __restrict__ rp, int* __restrict__ cur,
                               int* __restrict__ col, int e) {
    int i = blockIdx.x * 256 + threadIdx.x;
    if (i < e) {
        int d = dst[i];
        int p = rp[d] + atomicAdd(&cur[d], 1);
        col[p] = src[i];
    }
}

// ---------------- attention: one wave per dst node, 4 edge slots, online softmax, relu fused ----
// lane: es=lane>>4 (4 edge slots); l=lane&15 -> 8 dims at d0=l*8; head = l>>2
__global__ __launch_bounds__(256)
void attn_kernel(const _Float16* __restrict__ q, const _Float16* __restrict__ k,
                 const _Float16* __restrict__ v,
                 const int* __restrict__ rp, const int* __restrict__ deg,
                 const int* __restrict__ col,
                 _Float16* __restrict__ out, int n) {
    int w = threadIdx.x >> 6;
    int lane = threadIdx.x & 63;
    int node = blockIdx.x * 4 + w;
    if (node >= n) return;
    int es = lane >> 4;
    int l = lane & 15;
    int d0 = l * 8;
    float qf[8];
    {
        half8 qh = *(const half8*)(q + (size_t)node * 128 + d0);
#pragma unroll
        for (int j = 0; j < 8; ++j) qf[j] = (float)qh[j];
    }
    int start = rp[node], len = deg[node];
    float m = -1e30f, s = 0.f;
    float acc[8];
#pragma unroll
    for (int j = 0; j < 8; ++j) acc[j] = 0.f;

    for (int i = es; i < len; i += 4) {
        int srcn = col[start + i];
        half8 kf = *(const half8*)(k + (size_t)srcn * 128 + d0);
        float dot = 0.f;
#pragma unroll
        for (int j = 0; j < 8; ++j) dot += qf[j] * (float)kf[j];
        dot += __shfl_xor(dot, 1);
        dot += __shfl_xor(dot, 2);            // sum over the 4 lanes of this head
        float alpha = dot * 0.17677669529663689f;  // 1/sqrt(32)
        float nm = fmaxf(m, alpha);
        float fac = __expf(m - nm);           // m=-1e30 first iter -> 0
        float p = __expf(alpha - nm);
        half8 vf = *(const half8*)(v + (size_t)srcn * 128 + d0);
        s = s * fac + p;
#pragma unroll
        for (int j = 0; j < 8; ++j) acc[j] = acc[j] * fac + p * (float)vf[j];
        m = nm;
    }
    // merge the four edge slots (lane ^ 16, lane ^ 32)
#pragma unroll
    for (int half = 16; half <= 32; half <<= 1) {
        float mo = __shfl_xor(m, half);
        float so = __shfl_xor(s, half);
        float ao[8];
#pragma unroll
        for (int j = 0; j < 8; ++j) ao[j] = __shfl_xor(acc[j], half);
        float nm = fmaxf(m, mo);
        float f1 = __expf(m - nm);
        float f2 = __expf(mo - nm);
        s = s * f1 + so * f2;
#pragma unroll
        for (int j = 0; j < 8; ++j) acc[j] = acc[j] * f1 + ao[j] * f2;
        m = nm;
    }
    if (es == 0) {
        float inv = 1.f / (s + 1e-16f);
        half8 r;
#pragma unroll
        for (int j = 0; j < 8; ++j) r[j] = (_Float16)fmaxf(acc[j] * inv, 0.f);
        *(half8*)(out + (size_t)node * 128 + d0) = r;
    }
}

// ---------------- output head: concat(x1,x2,x3) @ out_w + out_b ----------------
__global__ void head_kernel(const _Float16* __restrict__ h0, const _Float16* __restrict__ h1,
                            const _Float16* __restrict__ h2, const int* __restrict__ gi,
                            const float* __restrict__ ow, const float* __restrict__ ob,
                            float* __restrict__ out, int bsz) {
    int idx = blockIdx.x * 256 + threadIdx.x;
    if (idx >= bsz * 5) return;
    int b = idx / 5, c = idx % 5;
    int g = gi[b];
    float acc = ob[c];
    const _Float16* r0 = h0 + (size_t)g * 32;
#pragma unroll
    for (int i = 0; i < 32; ++i) acc += (float)r0[i] * ow[i * 5 + c];
    const _Float16* r1 = h1 + (size_t)g * 128;
#pragma unroll
    for (int i = 0; i < 128; ++i) acc += (float)r1[i] * ow[(32 + i) * 5 + c];
    const _Float16* r2 = h2 + (size_t)g * 128;
#pragma unroll
    for (int i = 0; i < 128; ++i) acc += (float)r2[i] * ow[(160 + i) * 5 + c];
    out[idx] = acc;
}

extern "C" void kernel_launch(void* const* d_in, const int* in_sizes, int n_in,
                              void* d_out, int out_size, void* d_ws, size_t ws_size,
                              hipStream_t stream) {
    const float* x    = (const float*)d_in[0];
    const int*   ei   = (const int*)d_in[1];
    const float* dm   = (const float*)d_in[2];
    const int*   gi   = (const int*)d_in[3];
    const float* ew1  = (const float*)d_in[4];
    const float* eb1  = (const float*)d_in[5];
    const float* ew2  = (const float*)d_in[6];
    const float* eb2  = (const float*)d_in[7];
    const float* c1wq = (const float*)d_in[8];
    const float* c1bq = (const float*)d_in[9];
    const float* c1wk = (const float*)d_in[10];
    const float* c1bk = (const float*)d_in[11];
    const float* c1wv = (const float*)d_in[12];
    const float* c1bv = (const float*)d_in[13];
    const float* c2wq = (const float*)d_in[14];
    const float* c2bq = (const float*)d_in[15];
    const float* c2wk = (const float*)d_in[16];
    const float* c2bk = (const float*)d_in[17];
    const float* c2wv = (const float*)d_in[18];
    const float* c2bv = (const float*)d_in[19];
    const float* ow   = (const float*)d_in[20];
    const float* ob   = (const float*)d_in[21];
    float* out = (float*)d_out;

    int N = in_sizes[0] / 64;
    int E = in_sizes[1] / 2;
    int B = in_sizes[3];
    const int* srcv = ei;
    const int* dstv = ei + E;

    // workspace carve-up
    char* ws = (char*)d_ws;
    size_t off = 0;
    auto alloc = [&](size_t bytes) -> void* {
        void* p = ws + off;
        off += (bytes + 255) & ~(size_t)255;
        return p;
    };
    _Float16* h0  = (_Float16*)alloc((size_t)N * 32 * 2);
    _Float16* h1  = (_Float16*)alloc((size_t)N * 128 * 2);
    _Float16* h2  = (_Float16*)alloc((size_t)N * 128 * 2);
    _Float16* Q   = (_Float16*)alloc((size_t)N * 128 * 2);
    _Float16* K   = (_Float16*)alloc((size_t)N * 128 * 2);
    _Float16* V   = (_Float16*)alloc((size_t)N * 128 * 2);
    _Float16* WT1 = (_Float16*)alloc((size_t)3 * 128 * 32 * 2);
    _Float16* WT2 = (_Float16*)alloc((size_t)3 * 128 * 128 * 2);
    int* deg   = (int*)alloc((size_t)N * 4);
    int* rp    = (int*)alloc((size_t)N * 4);
    int* cur   = (int*)alloc((size_t)N * 4);
    int* colb  = (int*)alloc((size_t)E * 4);
    int* bsum  = (int*)alloc(4096);

    hipMemsetAsync(deg, 0, (size_t)N * 4, stream);
    hipMemsetAsync(cur, 0, (size_t)N * 4, stream);

    int eb = (E + 255) / 256;
    int nb = (N + 255) / 256;   // 196 <= 256 required by scan2
    wt_kernel<<<(3 * 128 * 32 + 255) / 256, 256, 0, stream>>>(c1wq, c1wk, c1wv, WT1, 32);
    wt_kernel<<<(3 * 128 * 128 + 255) / 256, 256, 0, stream>>>(c2wq, c2wk, c2wv, WT2, 128);
    hist_kernel<<<eb, 256, 0, stream>>>(dstv, deg, E);
    scan1_kernel<<<nb, 256, 0, stream>>>(deg, rp, bsum, N);
    scan2_kernel<<<1, 256, 0, stream>>>(bsum, nb);
    scan3_kernel<<<nb, 256, 0, stream>>>(rp, bsum, N);
    scatter_kernel<<<eb, 256, 0, stream>>>(srcv, dstv, rp, cur, colb, E);

    enc_kernel<<<(N + 7) / 8, 256, 0, stream>>>(x, ew1, eb1, ew2, eb2, h0, N);

    dim3 gq((N + 63) / 64, 6);
    // conv1: IN=32
    qkv_kernel<<<gq, 256, 0, stream>>>(h0, nullptr, WT1, c1bq, c1bk, c1bv, Q, K, V, N, 32);
    attn_kernel<<<(N + 3) / 4, 256, 0, stream>>>(Q, K, V, rp, deg, colb, h1, N);
    // conv2: IN=128, input = h1 * dm_mask (mask fused into staging; x2 gathers unmasked h1)
    qkv_kernel<<<gq, 256, 0, stream>>>(h1, dm, WT2, c2bq, c2bk, c2bv, Q, K, V, N, 128);
    attn_kernel<<<(N + 3) / 4, 256, 0, stream>>>(Q, K, V, rp, deg, colb, h2, N);

    head_kernel<<<(B * 5 + 255) / 256, 256, 0, stream>>>(h0, h1, h2, gi, ow, ob, out, B);
}

// Round 4
// 252.851 us; speedup vs baseline: 1.8470x; 1.1305x over previous
//
#include <hip/hip_runtime.h>
#include <math.h>

// DGNRNetwork: encoder MLP -> TransformerConv(32->4x32) -> mask -> TransformerConv(128->4x32) -> head
// N=50000, E=800000, B=1000, HID=32, HEADS=4, D1=128, FINAL=288
// fp16 downstream of encoder; qkv via MFMA 16x16x32_f16; attn = max-free softmax over CSR gathers
// of an interleaved KV buffer (per-node 256 halfs: K[0..127] | V[128..255]).

typedef _Float16 half8 __attribute__((ext_vector_type(8)));
typedef float f32x4 __attribute__((ext_vector_type(4)));

__device__ inline half8 h8zero() {
    half8 r;
#pragma unroll
    for (int j = 0; j < 8; ++j) r[j] = (_Float16)0.f;
    return r;
}

// ---------------- encoder: h0 = relu(relu(x@W1+b1)@W2+b2), fp16 out ----------------
__global__ __launch_bounds__(256)
void enc_kernel(const float* __restrict__ x,
                const float* __restrict__ w1, const float* __restrict__ b1,
                const float* __restrict__ w2, const float* __restrict__ b2,
                _Float16* __restrict__ h0, int n) {
    __shared__ float W1s[64 * 32];
    __shared__ float W2s[32 * 32];
    __shared__ float B1s[32], B2s[32];
    __shared__ float xs[8 * 64];
    __shared__ float hs[8 * 32];
    int t = threadIdx.x;
    for (int i = t; i < 64 * 32; i += 256) W1s[i] = w1[i];
    for (int i = t; i < 32 * 32; i += 256) W2s[i] = w2[i];
    if (t < 32) { B1s[t] = b1[t]; B2s[t] = b2[t]; }
    int bn = blockIdx.x * 8;
    if (t < 128) {  // 8 rows x 64 floats = 128 float4, contiguous
        int row = t >> 4;
        float4 val = make_float4(0.f, 0.f, 0.f, 0.f);
        if (bn + row < n) val = *(const float4*)(x + (size_t)bn * 64 + t * 4);
        ((float4*)xs)[t] = val;
    }
    __syncthreads();
    int nn = t >> 5, c = t & 31;
    float acc = B1s[c];
#pragma unroll
    for (int i = 0; i < 64; ++i) acc += xs[nn * 64 + i] * W1s[i * 32 + c];
    acc = fmaxf(acc, 0.f);
    hs[nn * 32 + c] = acc;
    __syncthreads();
    float acc2 = B2s[c];
#pragma unroll
    for (int i = 0; i < 32; ++i) acc2 += hs[nn * 32 + i] * W2s[i * 32 + c];
    acc2 = fmaxf(acc2, 0.f);
    int node = bn + nn;
    if (node < n) h0[(size_t)node * 32 + c] = (_Float16)acc2;
}

// ---------------- weight transpose+convert (both convs in one launch) ----------------
// WT[z*128+c][k] = Wz[k][c] (fp16)
__global__ void wt_kernel(const float* __restrict__ q1, const float* __restrict__ k1,
                          const float* __restrict__ v1, _Float16* __restrict__ WT1,
                          const float* __restrict__ q2, const float* __restrict__ k2,
                          const float* __restrict__ v2, _Float16* __restrict__ WT2) {
    int tid = blockIdx.x * 256 + threadIdx.x;
    const int n1 = 3 * 128 * 32;
    const int n2 = 3 * 128 * 128;
    if (tid < n1) {
        int z = tid / (128 * 32);
        int rem = tid % (128 * 32);
        int c = rem / 32, k = rem % 32;
        const float* w = (z == 0) ? q1 : ((z == 1) ? k1 : v1);
        WT1[tid] = (_Float16)w[k * 128 + c];
    } else {
        int i = tid - n1;
        if (i >= n2) return;
        int z = i / (128 * 128);
        int rem = i % (128 * 128);
        int c = rem / 128, k = rem % 128;
        const float* w = (z == 0) ? q2 : ((z == 1) ? k2 : v2);
        WT2[i] = (_Float16)w[k * 128 + c];
    }
}

// ---------------- qkv GEMM via MFMA: Y_z[n x 128] = (X .* mask?) @ Wz + bz -------------
// grid (ceil(n/64), 3): z = blockIdx.y. 256 thr = 4 waves (2x2): wr -> 32 rows, wc -> 64 cols.
// A-frag: lane row=l&15, k=(l>>4)*8+j ; B-frag: lane col=l&15, same k ; C/D: col=l&15, row=(l>>4)*4+reg.
__global__ __launch_bounds__(256)
void qkv_kernel(const _Float16* __restrict__ X, const float* __restrict__ mask,
                const _Float16* __restrict__ WT,
                const float* __restrict__ Bq, const float* __restrict__ Bk,
                const float* __restrict__ Bv,
                _Float16* __restrict__ Q, _Float16* __restrict__ KV,
                int n, int IN) {
    __shared__ _Float16 Xs[64 * 40];    // 64 rows x 32 halfs, padded to 40
    __shared__ _Float16 Ws[128 * 40];   // 128 cols x 32 halfs, padded
    int t = threadIdx.x;
    int z = blockIdx.y;
    int bm = blockIdx.x * 64;
    const float* Bz = (z == 0) ? Bq : ((z == 1) ? Bk : Bv);
    _Float16* Y;
    size_t ystride;
    if (z == 0) { Y = Q; ystride = 128; }
    else        { Y = KV + (z == 1 ? 0 : 128); ystride = 256; }

    int lane = t & 63, w = t >> 6;
    int wr = w >> 1, wc = w & 1;
    int fr = lane & 15, k0 = (lane >> 4) * 8;
    f32x4 acc[2][4];
#pragma unroll
    for (int i = 0; i < 2; ++i)
#pragma unroll
        for (int j = 0; j < 4; ++j)
#pragma unroll
            for (int r = 0; r < 4; ++r) acc[i][j][r] = 0.f;

    // staging roles: X -> row t>>2 (0..63), seg (t&3)*8 ; W -> rows t>>2 and 64+(t>>2)
    int srow = t >> 2, sseg = (t & 3) * 8;
    int snode = bm + srow;
    const _Float16* xbase = X + (size_t)snode * IN + sseg;
    const _Float16* wbase = WT + (size_t)(z * 128) * IN + sseg;
    bool xvalid = (snode < n);
    if (xvalid && mask) xvalid = (mask[snode] != 0.f);   // mask is exactly 0/1

    for (int kt = 0; kt < IN; kt += 32) {
        half8 xv = h8zero();
        if (xvalid) xv = *(const half8*)(xbase + kt);
        half8 wv0 = *(const half8*)(wbase + (size_t)srow * IN + kt);
        half8 wv1 = *(const half8*)(wbase + (size_t)(64 + srow) * IN + kt);
        __syncthreads();   // protect LDS reuse from previous iteration
        *(half8*)&Xs[srow * 40 + sseg] = xv;
        *(half8*)&Ws[srow * 40 + sseg] = wv0;
        *(half8*)&Ws[(64 + srow) * 40 + sseg] = wv1;
        __syncthreads();
        half8 a0 = *(const half8*)&Xs[(wr * 32 + fr) * 40 + k0];
        half8 a1 = *(const half8*)&Xs[(wr * 32 + 16 + fr) * 40 + k0];
#pragma unroll
        for (int tc = 0; tc < 4; ++tc) {
            half8 b = *(const half8*)&Ws[(wc * 64 + tc * 16 + fr) * 40 + k0];
            acc[0][tc] = __builtin_amdgcn_mfma_f32_16x16x32_f16(a0, b, acc[0][tc], 0, 0, 0);
            acc[1][tc] = __builtin_amdgcn_mfma_f32_16x16x32_f16(a1, b, acc[1][tc], 0, 0, 0);
        }
    }
#pragma unroll
    for (int tc = 0; tc < 4; ++tc) {
        int colc = wc * 64 + tc * 16 + fr;
        float bias = Bz[colc];
#pragma unroll
        for (int tr = 0; tr < 2; ++tr) {
#pragma unroll
            for (int reg = 0; reg < 4; ++reg) {
                int node = bm + wr * 32 + tr * 16 + (lane >> 4) * 4 + reg;
                if (node < n) Y[(size_t)node * ystride + colc] = (_Float16)(acc[tr][tc][reg] + bias);
            }
        }
    }
}

// ---------------- CSR build ----------------
__global__ void hist_kernel(const int* __restrict__ dst, int* __restrict__ deg,
                            int* __restrict__ eslot, int e) {
    int i = blockIdx.x * 256 + threadIdx.x;
    if (i < e) eslot[i] = atomicAdd(&deg[dst[i]], 1);
}
__global__ void scan1_kernel(const int* __restrict__ deg, int* __restrict__ rp,
                             int* __restrict__ bsum, int n) {
    __shared__ int s[256];
    int t = threadIdx.x;
    int gid = blockIdx.x * 256 + t;
    int v = (gid < n) ? deg[gid] : 0;
    s[t] = v;
    __syncthreads();
#pragma unroll
    for (int off = 1; off < 256; off <<= 1) {
        int tv = (t >= off) ? s[t - off] : 0;
        __syncthreads();
        s[t] += tv;
        __syncthreads();
    }
    if (gid < n) rp[gid] = s[t] - v;            // exclusive within chunk
    if (t == 255) bsum[blockIdx.x] = s[255];    // chunk total
}
__global__ void scan2_kernel(int* bsum, int nb) {  // nb <= 256
    __shared__ int s[256];
    int t = threadIdx.x;
    int v = (t < nb) ? bsum[t] : 0;
    s[t] = v;
    __syncthreads();
#pragma unroll
    for (int off = 1; off < 256; off <<= 1) {
        int tv = (t >= off) ? s[t - off] : 0;
        __syncthreads();
        s[t] += tv;
        __syncthreads();
    }
    if (t < nb) bsum[t] = s[t] - v;             // exclusive
}
__global__ void scan3_kernel(int* rp, const int* __restrict__ bsum, int n) {
    int gid = blockIdx.x * 256 + threadIdx.x;
    if (gid < n) rp[gid] += bsum[blockIdx.x];
}
__global__ void scatter_kernel(const int* __restrict__ src, const int* __restrict__ dst,
                               const int* __restrict__ rp, const int* __restrict__ eslot,
                               int* __restrict__ col, int e) {
    int i = blockIdx.x * 256 + threadIdx.x;
    if (i < e) col[rp[dst[i]] + eslot[i]] = src[i];
}

// ---------------- attention: one wave per dst node, 4 edge slots, MAX-FREE softmax ----------
// softmax is shift-invariant; logits here are O(1) so exp2 with +/-120 clamp is exact enough.
// lane: es=lane>>4 (4 edge slots); l=lane&15 -> 8 dims at d0=l*8; head = l>>2
__global__ __launch_bounds__(256)
void attn_kernel(const _Float16* __restrict__ q, const _Float16* __restrict__ kv,
                 const int* __restrict__ rp, const int* __restrict__ deg,
                 const int* __restrict__ col,
                 _Float16* __restrict__ out, int n) {
    int w = threadIdx.x >> 6;
    int lane = threadIdx.x & 63;
    int node = blockIdx.x * 4 + w;
    if (node >= n) return;
    int es = lane >> 4;
    int l = lane & 15;
    int d0 = l * 8;
    half8 qh = *(const half8*)(q + (size_t)node * 128 + d0);
    int start = rp[node], len = deg[node];
    float s = 0.f;
    float acc[8];
#pragma unroll
    for (int j = 0; j < 8; ++j) acc[j] = 0.f;
    const float sc = 0.17677669529663689f * 1.4426950408889634f;  // 1/sqrt(32) * log2(e)

    for (int i = es; i < len; i += 4) {
        int srcn = col[start + i];
        const _Float16* row = kv + (size_t)srcn * 256 + d0;
        half8 kf = *(const half8*)row;
        float dot = 0.f;
#pragma unroll
        for (int j = 0; j < 8; ++j) dot += (float)qh[j] * (float)kf[j];
        dot += __shfl_xor(dot, 1);
        dot += __shfl_xor(dot, 2);            // sum over the 4 lanes of this head
        float a = fminf(fmaxf(dot * sc, -120.f), 120.f);
        float p = __builtin_amdgcn_exp2f(a);
        half8 vf = *(const half8*)(row + 128);
        s += p;
#pragma unroll
        for (int j = 0; j < 8; ++j) acc[j] += p * (float)vf[j];
    }
    // merge the four edge slots (pure sums — no max bookkeeping)
#pragma unroll
    for (int half = 16; half <= 32; half <<= 1) {
        s += __shfl_xor(s, half);
#pragma unroll
        for (int j = 0; j < 8; ++j) acc[j] += __shfl_xor(acc[j], half);
    }
    if (es == 0) {
        float inv = 1.f / (s + 1e-16f);
        half8 r;
#pragma unroll
        for (int j = 0; j < 8; ++j) r[j] = (_Float16)fmaxf(acc[j] * inv, 0.f);
        *(half8*)(out + (size_t)node * 128 + d0) = r;
    }
}

// ---------------- output head: concat(x1,x2,x3) @ out_w + out_b ----------------
__global__ void head_kernel(const _Float16* __restrict__ h0, const _Float16* __restrict__ h1,
                            const _Float16* __restrict__ h2, const int* __restrict__ gi,
                            const float* __restrict__ ow, const float* __restrict__ ob,
                            float* __restrict__ out, int bsz) {
    int idx = blockIdx.x * 256 + threadIdx.x;
    if (idx >= bsz * 5) return;
    int b = idx / 5, c = idx % 5;
    int g = gi[b];
    float acc = ob[c];
    const _Float16* r0 = h0 + (size_t)g * 32;
#pragma unroll
    for (int i = 0; i < 32; ++i) acc += (float)r0[i] * ow[i * 5 + c];
    const _Float16* r1 = h1 + (size_t)g * 128;
#pragma unroll
    for (int i = 0; i < 128; ++i) acc += (float)r1[i] * ow[(32 + i) * 5 + c];
    const _Float16* r2 = h2 + (size_t)g * 128;
#pragma unroll
    for (int i = 0; i < 128; ++i) acc += (float)r2[i] * ow[(160 + i) * 5 + c];
    out[idx] = acc;
}

extern "C" void kernel_launch(void* const* d_in, const int* in_sizes, int n_in,
                              void* d_out, int out_size, void* d_ws, size_t ws_size,
                              hipStream_t stream) {
    const float* x    = (const float*)d_in[0];
    const int*   ei   = (const int*)d_in[1];
    const float* dm   = (const float*)d_in[2];
    const int*   gi   = (const int*)d_in[3];
    const float* ew1  = (const float*)d_in[4];
    const float* eb1  = (const float*)d_in[5];
    const float* ew2  = (const float*)d_in[6];
    const float* eb2  = (const float*)d_in[7];
    const float* c1wq = (const float*)d_in[8];
    const float* c1bq = (const float*)d_in[9];
    const float* c1wk = (const float*)d_in[10];
    const float* c1bk = (const float*)d_in[11];
    const float* c1wv = (const float*)d_in[12];
    const float* c1bv = (const float*)d_in[13];
    const float* c2wq = (const float*)d_in[14];
    const float* c2bq = (const float*)d_in[15];
    const float* c2wk = (const float*)d_in[16];
    const float* c2bk = (const float*)d_in[17];
    const float* c2wv = (const float*)d_in[18];
    const float* c2bv = (const float*)d_in[19];
    const float* ow   = (const float*)d_in[20];
    const float* ob   = (const float*)d_in[21];
    float* out = (float*)d_out;

    int N = in_sizes[0] / 64;
    int E = in_sizes[1] / 2;
    int B = in_sizes[3];
    const int* srcv = ei;
    const int* dstv = ei + E;

    // workspace carve-up
    char* ws = (char*)d_ws;
    size_t off = 0;
    auto alloc = [&](size_t bytes) -> void* {
        void* p = ws + off;
        off += (bytes + 255) & ~(size_t)255;
        return p;
    };
    _Float16* h0   = (_Float16*)alloc((size_t)N * 32 * 2);
    _Float16* h1   = (_Float16*)alloc((size_t)N * 128 * 2);
    _Float16* h2   = (_Float16*)alloc((size_t)N * 128 * 2);
    _Float16* Q    = (_Float16*)alloc((size_t)N * 128 * 2);
    _Float16* KV   = (_Float16*)alloc((size_t)N * 256 * 2);
    _Float16* WT1  = (_Float16*)alloc((size_t)3 * 128 * 32 * 2);
    _Float16* WT2  = (_Float16*)alloc((size_t)3 * 128 * 128 * 2);
    int* deg   = (int*)alloc((size_t)N * 4);
    int* rp    = (int*)alloc((size_t)N * 4);
    int* eslot = (int*)alloc((size_t)E * 4);
    int* colb  = (int*)alloc((size_t)E * 4);
    int* bsum  = (int*)alloc(4096);

    hipMemsetAsync(deg, 0, (size_t)N * 4, stream);

    int eb = (E + 255) / 256;
    int nb = (N + 255) / 256;   // 196 <= 256 required by scan2
    wt_kernel<<<(3 * 128 * 32 + 3 * 128 * 128 + 255) / 256, 256, 0, stream>>>(
        c1wq, c1wk, c1wv, WT1, c2wq, c2wk, c2wv, WT2);
    hist_kernel<<<eb, 256, 0, stream>>>(dstv, deg, eslot, E);
    scan1_kernel<<<nb, 256, 0, stream>>>(deg, rp, bsum, N);
    scan2_kernel<<<1, 256, 0, stream>>>(bsum, nb);
    scan3_kernel<<<nb, 256, 0, stream>>>(rp, bsum, N);
    scatter_kernel<<<eb, 256, 0, stream>>>(srcv, dstv, rp, eslot, colb, E);

    enc_kernel<<<(N + 7) / 8, 256, 0, stream>>>(x, ew1, eb1, ew2, eb2, h0, N);

    dim3 gq((N + 63) / 64, 3);
    // conv1: IN=32
    qkv_kernel<<<gq, 256, 0, stream>>>(h0, nullptr, WT1, c1bq, c1bk, c1bv, Q, KV, N, 32);
    attn_kernel<<<(N + 3) / 4, 256, 0, stream>>>(Q, KV, rp, deg, colb, h1, N);
    // conv2: IN=128, input = h1 * dm_mask (mask fused into staging; x2 gathers unmasked h1)
    qkv_kernel<<<gq, 256, 0, stream>>>(h1, dm, WT2, c2bq, c2bk, c2bv, Q, KV, N, 128);
    attn_kernel<<<(N + 3) / 4, 256, 0, stream>>>(Q, KV, rp, deg, colb, h2, N);

    head_kernel<<<(B * 5 + 255) / 256, 256, 0, stream>>>(h0, h1, h2, gi, ow, ob, out, B);
}

// Round 5
// 244.902 us; speedup vs baseline: 1.9070x; 1.0325x over previous
//
#include <hip/hip_runtime.h>
#include <math.h>

// DGNRNetwork: encoder MLP -> TransformerConv(32->4x32) -> mask -> TransformerConv(128->4x32) -> head
// N=50000, E=800000, B=1000, HID=32, HEADS=4, D1=128, FINAL=288
// fp16 downstream of encoder; qkv via MFMA 16x16x32_f16; attn = max-free softmax over CSR gathers
// of interleaved KV rows (256 halfs: K[0..127] | V[128..255]).
// Launch graph (10 nodes): memset(deg) -> prep[wt|hist|enc] -> scan1|qkv1 -> scan2 -> scan3
//                          -> scatter -> attn1 -> qkv2 -> attn2 -> head

typedef _Float16 half8 __attribute__((ext_vector_type(8)));
typedef float f32x4 __attribute__((ext_vector_type(4)));

__device__ inline half8 h8zero() {
    half8 r;
#pragma unroll
    for (int j = 0; j < 8; ++j) r[j] = (_Float16)0.f;
    return r;
}

// ---------------- encoder body: h0 = relu(relu(x@W1+b1)@W2+b2), fp16 out ----------------
__device__ __forceinline__ void enc_body(const float* __restrict__ x,
                                         const float* __restrict__ w1, const float* __restrict__ b1,
                                         const float* __restrict__ w2, const float* __restrict__ b2,
                                         _Float16* __restrict__ h0, int n, int bn,
                                         float* __restrict__ smem) {
    float* W1s = smem;          // 2048
    float* W2s = smem + 2048;   // 1024
    float* B1s = smem + 3072;   // 32
    float* B2s = smem + 3104;   // 32
    float* xs  = smem + 3136;   // 512
    float* hs  = smem + 3648;   // 256
    int t = threadIdx.x;
    for (int i = t; i < 64 * 32; i += 256) W1s[i] = w1[i];
    for (int i = t; i < 32 * 32; i += 256) W2s[i] = w2[i];
    if (t < 32) { B1s[t] = b1[t]; B2s[t] = b2[t]; }
    if (t < 128) {  // 8 rows x 64 floats = 128 float4, contiguous
        int row = t >> 4;
        float4 val = make_float4(0.f, 0.f, 0.f, 0.f);
        if (bn + row < n) val = *(const float4*)(x + (size_t)bn * 64 + t * 4);
        ((float4*)xs)[t] = val;
    }
    __syncthreads();
    int nn = t >> 5, c = t & 31;
    float acc = B1s[c];
#pragma unroll
    for (int i = 0; i < 64; ++i) acc += xs[nn * 64 + i] * W1s[i * 32 + c];
    acc = fmaxf(acc, 0.f);
    hs[nn * 32 + c] = acc;
    __syncthreads();
    float acc2 = B2s[c];
#pragma unroll
    for (int i = 0; i < 32; ++i) acc2 += hs[nn * 32 + i] * W2s[i * 32 + c];
    acc2 = fmaxf(acc2, 0.f);
    int node = bn + nn;
    if (node < n) h0[(size_t)node * 32 + c] = (_Float16)acc2;
}

// ---------------- prep: wt | hist | enc fused by blockIdx range ----------------
__global__ __launch_bounds__(256)
void prep_kernel(const float* __restrict__ x,
                 const float* __restrict__ ew1, const float* __restrict__ eb1,
                 const float* __restrict__ ew2, const float* __restrict__ eb2,
                 _Float16* __restrict__ h0,
                 const float* __restrict__ q1, const float* __restrict__ k1,
                 const float* __restrict__ v1, _Float16* __restrict__ WT1,
                 const float* __restrict__ q2, const float* __restrict__ k2,
                 const float* __restrict__ v2, _Float16* __restrict__ WT2,
                 const int* __restrict__ dstv, int* __restrict__ deg, int* __restrict__ eslot,
                 int n, int e, int wtb, int histb) {
    __shared__ float smem[3904];
    int b = blockIdx.x, t = threadIdx.x;
    if (b < wtb) {
        // WT[z*128+c][k] = Wz[k][c] (fp16), both convs back to back
        int tid = b * 256 + t;
        const int n1 = 3 * 128 * 32;
        if (tid < n1) {
            int z = tid / (128 * 32);
            int rem = tid % (128 * 32);
            int c = rem / 32, k = rem % 32;
            const float* w = (z == 0) ? q1 : ((z == 1) ? k1 : v1);
            WT1[tid] = (_Float16)w[k * 128 + c];
        } else {
            int i = tid - n1;
            if (i < 3 * 128 * 128) {
                int z = i / (128 * 128);
                int rem = i % (128 * 128);
                int c = rem / 128, k = rem % 128;
                const float* w = (z == 0) ? q2 : ((z == 1) ? k2 : v2);
                WT2[i] = (_Float16)w[k * 128 + c];
            }
        }
    } else if (b < wtb + histb) {
        int i = (b - wtb) * 256 + t;
        if (i < e) eslot[i] = atomicAdd(&deg[dstv[i]], 1);
    } else {
        enc_body(x, ew1, eb1, ew2, eb2, h0, n, (b - wtb - histb) * 8, smem);
    }
}

// ---------------- qkv GEMM body via MFMA: Y_z[n x 128] = (X .* mask?) @ Wz + bz -------------
// 256 thr = 4 waves (2x2): wr -> 32 rows, wc -> 64 cols. BM=64, K-tile=32.
// A-frag: lane row=l&15, k=(l>>4)*8+j ; B-frag: lane col=l&15, same k ; C/D: col=l&15, row=(l>>4)*4+reg.
__device__ __forceinline__ void qkv_body(const _Float16* __restrict__ X, const float* __restrict__ mask,
                                         const _Float16* __restrict__ WT,
                                         const float* __restrict__ Bq, const float* __restrict__ Bk,
                                         const float* __restrict__ Bv,
                                         _Float16* __restrict__ Q, _Float16* __restrict__ KV,
                                         int n, int IN, int bx, int z,
                                         _Float16* __restrict__ Xs, _Float16* __restrict__ Ws) {
    int t = threadIdx.x;
    int bm = bx * 64;
    const float* Bz = (z == 0) ? Bq : ((z == 1) ? Bk : Bv);
    _Float16* Y;
    size_t ystride;
    if (z == 0) { Y = Q; ystride = 128; }
    else        { Y = KV + (z == 1 ? 0 : 128); ystride = 256; }

    int lane = t & 63, w = t >> 6;
    int wr = w >> 1, wc = w & 1;
    int fr = lane & 15, k0 = (lane >> 4) * 8;
    f32x4 acc[2][4];
#pragma unroll
    for (int i = 0; i < 2; ++i)
#pragma unroll
        for (int j = 0; j < 4; ++j)
#pragma unroll
            for (int r = 0; r < 4; ++r) acc[i][j][r] = 0.f;

    // staging roles: X -> row t>>2 (0..63), seg (t&3)*8 ; W -> rows t>>2 and 64+(t>>2)
    int srow = t >> 2, sseg = (t & 3) * 8;
    int snode = bm + srow;
    const _Float16* xbase = X + (size_t)snode * IN + sseg;
    const _Float16* wbase = WT + (size_t)(z * 128) * IN + sseg;
    bool xvalid = (snode < n);
    if (xvalid && mask) xvalid = (mask[snode] != 0.f);   // mask is exactly 0/1

    for (int kt = 0; kt < IN; kt += 32) {
        half8 xv = h8zero();
        if (xvalid) xv = *(const half8*)(xbase + kt);
        half8 wv0 = *(const half8*)(wbase + (size_t)srow * IN + kt);
        half8 wv1 = *(const half8*)(wbase + (size_t)(64 + srow) * IN + kt);
        __syncthreads();   // protect LDS reuse from previous iteration
        *(half8*)&Xs[srow * 40 + sseg] = xv;
        *(half8*)&Ws[srow * 40 + sseg] = wv0;
        *(half8*)&Ws[(64 + srow) * 40 + sseg] = wv1;
        __syncthreads();
        half8 a0 = *(const half8*)&Xs[(wr * 32 + fr) * 40 + k0];
        half8 a1 = *(const half8*)&Xs[(wr * 32 + 16 + fr) * 40 + k0];
#pragma unroll
        for (int tc = 0; tc < 4; ++tc) {
            half8 bfr = *(const half8*)&Ws[(wc * 64 + tc * 16 + fr) * 40 + k0];
            acc[0][tc] = __builtin_amdgcn_mfma_f32_16x16x32_f16(a0, bfr, acc[0][tc], 0, 0, 0);
            acc[1][tc] = __builtin_amdgcn_mfma_f32_16x16x32_f16(a1, bfr, acc[1][tc], 0, 0, 0);
        }
    }
#pragma unroll
    for (int tc = 0; tc < 4; ++tc) {
        int colc = wc * 64 + tc * 16 + fr;
        float bias = Bz[colc];
#pragma unroll
        for (int tr = 0; tr < 2; ++tr) {
#pragma unroll
            for (int reg = 0; reg < 4; ++reg) {
                int node = bm + wr * 32 + tr * 16 + (lane >> 4) * 4 + reg;
                if (node < n) Y[(size_t)node * ystride + colc] = (_Float16)(acc[tr][tc][reg] + bias);
            }
        }
    }
}

// ---------------- scan1 | qkv(conv1) fused ----------------
__global__ __launch_bounds__(256)
void scan1_qkv1_kernel(const int* __restrict__ deg, int* __restrict__ rp,
                       int* __restrict__ bsum, int n, int nb,
                       const _Float16* __restrict__ h0, const _Float16* __restrict__ WT1,
                       const float* __restrict__ bq, const float* __restrict__ bk,
                       const float* __restrict__ bv,
                       _Float16* __restrict__ Q, _Float16* __restrict__ KV, int nqx) {
    __shared__ _Float16 sm[64 * 40 + 128 * 40];   // 15360 B (scan uses first 1 KB)
    int b = blockIdx.x;
    if (b < nb) {
        int* s = (int*)sm;
        int t = threadIdx.x;
        int gid = b * 256 + t;
        int v = (gid < n) ? deg[gid] : 0;
        s[t] = v;
        __syncthreads();
#pragma unroll
        for (int off = 1; off < 256; off <<= 1) {
            int tv = (t >= off) ? s[t - off] : 0;
            __syncthreads();
            s[t] += tv;
            __syncthreads();
        }
        if (gid < n) rp[gid] = s[t] - v;        // exclusive within chunk
        if (t == 255) bsum[b] = s[255];         // chunk total
    } else {
        int r = b - nb;
        int z = r / nqx, bx = r % nqx;
        qkv_body(h0, nullptr, WT1, bq, bk, bv, Q, KV, n, 32, bx, z, sm, sm + 64 * 40);
    }
}

// ---------------- standalone qkv (conv2) ----------------
__global__ __launch_bounds__(256)
void qkv2_kernel(const _Float16* __restrict__ X, const float* __restrict__ mask,
                 const _Float16* __restrict__ WT,
                 const float* __restrict__ Bq, const float* __restrict__ Bk,
                 const float* __restrict__ Bv,
                 _Float16* __restrict__ Q, _Float16* __restrict__ KV, int n, int IN) {
    __shared__ _Float16 Xs[64 * 40];
    __shared__ _Float16 Ws[128 * 40];
    qkv_body(X, mask, WT, Bq, Bk, Bv, Q, KV, n, IN, blockIdx.x, blockIdx.y, Xs, Ws);
}

// ---------------- CSR scan tail + scatter ----------------
__global__ void scan2_kernel(int* bsum, int nb) {  // nb <= 256
    __shared__ int s[256];
    int t = threadIdx.x;
    int v = (t < nb) ? bsum[t] : 0;
    s[t] = v;
    __syncthreads();
#pragma unroll
    for (int off = 1; off < 256; off <<= 1) {
        int tv = (t >= off) ? s[t - off] : 0;
        __syncthreads();
        s[t] += tv;
        __syncthreads();
    }
    if (t < nb) bsum[t] = s[t] - v;             // exclusive
}
__global__ void scan3_kernel(int* rp, const int* __restrict__ bsum, int n) {
    int gid = blockIdx.x * 256 + threadIdx.x;
    if (gid < n) rp[gid] += bsum[blockIdx.x];
}
__global__ void scatter_kernel(const int* __restrict__ src, const int* __restrict__ dst,
                               const int* __restrict__ rp, const int* __restrict__ eslot,
                               int* __restrict__ col, int e) {
    int i = blockIdx.x * 256 + threadIdx.x;
    if (i < e) col[rp[dst[i]] + eslot[i]] = src[i];
}

// ---------------- attention: one wave per dst node, 4 edge slots, MAX-FREE softmax ----------
// softmax is shift-invariant; logits here are O(1) so exp2 with +/-120 clamp is exact enough.
// lane: es=lane>>4 (4 edge slots); l=lane&15 -> 8 dims at d0=l*8; head = l>>2
__global__ __launch_bounds__(256)
void attn_kernel(const _Float16* __restrict__ q, const _Float16* __restrict__ kv,
                 const int* __restrict__ rp, const int* __restrict__ deg,
                 const int* __restrict__ col,
                 _Float16* __restrict__ out, int n) {
    int w = threadIdx.x >> 6;
    int lane = threadIdx.x & 63;
    int node = blockIdx.x * 4 + w;
    if (node >= n) return;
    int es = lane >> 4;
    int l = lane & 15;
    int d0 = l * 8;
    float qf[8];
    {
        half8 qh = *(const half8*)(q + (size_t)node * 128 + d0);
#pragma unroll
        for (int j = 0; j < 8; ++j) qf[j] = (float)qh[j];
    }
    int start = rp[node], len = deg[node];
    float s = 0.f;
    float acc[8];
#pragma unroll
    for (int j = 0; j < 8; ++j) acc[j] = 0.f;
    const float sc = 0.17677669529663689f * 1.4426950408889634f;  // 1/sqrt(32) * log2(e)

    for (int i = es; i < len; i += 4) {
        int srcn = col[start + i];
        const _Float16* row = kv + (size_t)srcn * 256 + d0;
        half8 kf = *(const half8*)row;
        float dot = 0.f;
#pragma unroll
        for (int j = 0; j < 8; ++j) dot += qf[j] * (float)kf[j];
        dot += __shfl_xor(dot, 1);
        dot += __shfl_xor(dot, 2);            // sum over the 4 lanes of this head
        float a = fminf(fmaxf(dot * sc, -120.f), 120.f);
        float p = __builtin_amdgcn_exp2f(a);
        half8 vf = *(const half8*)(row + 128);
        s += p;
#pragma unroll
        for (int j = 0; j < 8; ++j) acc[j] += p * (float)vf[j];
    }
    // merge the four edge slots (pure sums — no max bookkeeping)
#pragma unroll
    for (int half = 16; half <= 32; half <<= 1) {
        s += __shfl_xor(s, half);
#pragma unroll
        for (int j = 0; j < 8; ++j) acc[j] += __shfl_xor(acc[j], half);
    }
    if (es == 0) {
        float inv = 1.f / (s + 1e-16f);
        half8 r;
#pragma unroll
        for (int j = 0; j < 8; ++j) r[j] = (_Float16)fmaxf(acc[j] * inv, 0.f);
        *(half8*)(out + (size_t)node * 128 + d0) = r;
    }
}

// ---------------- output head: concat(x1,x2,x3) @ out_w + out_b ----------------
__global__ void head_kernel(const _Float16* __restrict__ h0, const _Float16* __restrict__ h1,
                            const _Float16* __restrict__ h2, const int* __restrict__ gi,
                            const float* __restrict__ ow, const float* __restrict__ ob,
                            float* __restrict__ out, int bsz) {
    int idx = blockIdx.x * 256 + threadIdx.x;
    if (idx >= bsz * 5) return;
    int b = idx / 5, c = idx % 5;
    int g = gi[b];
    float acc = ob[c];
    const _Float16* r0 = h0 + (size_t)g * 32;
#pragma unroll
    for (int i = 0; i < 32; ++i) acc += (float)r0[i] * ow[i * 5 + c];
    const _Float16* r1 = h1 + (size_t)g * 128;
#pragma unroll
    for (int i = 0; i < 128; ++i) acc += (float)r1[i] * ow[(32 + i) * 5 + c];
    const _Float16* r2 = h2 + (size_t)g * 128;
#pragma unroll
    for (int i = 0; i < 128; ++i) acc += (float)r2[i] * ow[(160 + i) * 5 + c];
    out[idx] = acc;
}

extern "C" void kernel_launch(void* const* d_in, const int* in_sizes, int n_in,
                              void* d_out, int out_size, void* d_ws, size_t ws_size,
                              hipStream_t stream) {
    const float* x    = (const float*)d_in[0];
    const int*   ei   = (const int*)d_in[1];
    const float* dm   = (const float*)d_in[2];
    const int*   gi   = (const int*)d_in[3];
    const float* ew1  = (const float*)d_in[4];
    const float* eb1  = (const float*)d_in[5];
    const float* ew2  = (const float*)d_in[6];
    const float* eb2  = (const float*)d_in[7];
    const float* c1wq = (const float*)d_in[8];
    const float* c1bq = (const float*)d_in[9];
    const float* c1wk = (const float*)d_in[10];
    const float* c1bk = (const float*)d_in[11];
    const float* c1wv = (const float*)d_in[12];
    const float* c1bv = (const float*)d_in[13];
    const float* c2wq = (const float*)d_in[14];
    const float* c2bq = (const float*)d_in[15];
    const float* c2wk = (const float*)d_in[16];
    const float* c2bk = (const float*)d_in[17];
    const float* c2wv = (const float*)d_in[18];
    const float* c2bv = (const float*)d_in[19];
    const float* ow   = (const float*)d_in[20];
    const float* ob   = (const float*)d_in[21];
    float* out = (float*)d_out;

    int N = in_sizes[0] / 64;
    int E = in_sizes[1] / 2;
    int B = in_sizes[3];
    const int* srcv = ei;
    const int* dstv = ei + E;

    // workspace carve-up
    char* ws = (char*)d_ws;
    size_t off = 0;
    auto alloc = [&](size_t bytes) -> void* {
        void* p = ws + off;
        off += (bytes + 255) & ~(size_t)255;
        return p;
    };
    _Float16* h0   = (_Float16*)alloc((size_t)N * 32 * 2);
    _Float16* h1   = (_Float16*)alloc((size_t)N * 128 * 2);
    _Float16* h2   = (_Float16*)alloc((size_t)N * 128 * 2);
    _Float16* Q    = (_Float16*)alloc((size_t)N * 128 * 2);
    _Float16* KV   = (_Float16*)alloc((size_t)N * 256 * 2);
    _Float16* WT1  = (_Float16*)alloc((size_t)3 * 128 * 32 * 2);
    _Float16* WT2  = (_Float16*)alloc((size_t)3 * 128 * 128 * 2);
    int* deg   = (int*)alloc((size_t)N * 4);
    int* rp    = (int*)alloc((size_t)N * 4);
    int* eslot = (int*)alloc((size_t)E * 4);
    int* colb  = (int*)alloc((size_t)E * 4);
    int* bsum  = (int*)alloc(4096);

    hipMemsetAsync(deg, 0, (size_t)N * 4, stream);

    int eb = (E + 255) / 256;          // 3125
    int nb = (N + 255) / 256;          // 196 <= 256 required by scan2
    int nqx = (N + 63) / 64;           // 782
    int wtb = (3 * 128 * 32 + 3 * 128 * 128 + 255) / 256;   // 240

    prep_kernel<<<wtb + eb + (N + 7) / 8, 256, 0, stream>>>(
        x, ew1, eb1, ew2, eb2, h0,
        c1wq, c1wk, c1wv, WT1, c2wq, c2wk, c2wv, WT2,
        dstv, deg, eslot, N, E, wtb, eb);

    scan1_qkv1_kernel<<<nb + 3 * nqx, 256, 0, stream>>>(
        deg, rp, bsum, N, nb, h0, WT1, c1bq, c1bk, c1bv, Q, KV, nqx);

    scan2_kernel<<<1, 256, 0, stream>>>(bsum, nb);
    scan3_kernel<<<nb, 256, 0, stream>>>(rp, bsum, N);
    scatter_kernel<<<eb, 256, 0, stream>>>(srcv, dstv, rp, eslot, colb, E);

    attn_kernel<<<(N + 3) / 4, 256, 0, stream>>>(Q, KV, rp, deg, colb, h1, N);

    dim3 gq(nqx, 3);
    // conv2: IN=128, input = h1 * dm_mask (mask fused into staging; x2 gathers unmasked h1)
    qkv2_kernel<<<gq, 256, 0, stream>>>(h1, dm, WT2, c2bq, c2bk, c2bv, Q, KV, N, 128);
    attn_kernel<<<(N + 3) / 4, 256, 0, stream>>>(Q, KV, rp, deg, colb, h2, N);

    head_kernel<<<(B * 5 + 255) / 256, 256, 0, stream>>>(h0, h1, h2, gi, ow, ob, out, B);
}